// Round 1
// baseline (89.735 us; speedup 1.0000x reference)
//
#include <hip/hip_runtime.h>

// BatchInfoNCELoss: B=9, H=W=768, C=3, PATCH=3 (D=27), RADIUS=2 -> M=13 offsets,
// N_SAMPLES=100, TEMPERATURE=0.5, K=B-1=8.
//
// final = sum_n [ sum_{b, j!=b, m valid} dot(a[b,n], v[j,n,m])^2 ]
//               * (1/T^2) / (K * counts_n * B * N)
// where a[b,n] == v[b,n,m=6] (offset (0,0)), vectors are edge-clamped 3x3x3
// patches normalized to unit L2.

constexpr int BB = 9;
constexpr int HH = 768;
constexpr int WW = 768;
constexpr int CC = 3;
constexpr int D  = 27;   // PATCH*PATCH*C
constexpr int M  = 13;   // offsets with dy^2+dx^2 <= 4
constexpr int NS = 100;  // anchors
constexpr int M0 = 6;    // index of offset (0,0) in dy-major order

__global__ __launch_bounds__(128)
void BatchInfoNCELoss_anchor_kernel(const float* __restrict__ latents,
                                    const int* __restrict__ aidx,
                                    float* __restrict__ partial) {
    const int n = blockIdx.x;   // anchor id
    const int t = threadIdx.x;  // 0..127

    __shared__ float v[BB * M][D + 1];  // 117 normalized patch vectors (+1 pad)
    __shared__ float wsum[2];

    const int ODY[M] = {-2, -1, -1, -1, 0, 0, 0, 0, 0, 1, 1, 1, 2};
    const int ODX[M] = { 0, -1,  0,  1,-2,-1, 0, 1, 2,-1, 0, 1, 0};

    const int apos = aidx[n];
    const int ay = apos / WW;
    const int ax = apos - ay * WW;

    // Stage 1: compute 117 normalized patch vectors into LDS.
    for (int task = t; task < BB * M; task += 128) {
        const int b = task / M;
        const int m = task - b * M;
        const int ny = ay + ODY[m];
        const int nx = ax + ODX[m];
        // clipped position (reference clips pos; invalid ones masked later)
        const int cy = min(max(ny, 0), HH - 1);
        const int cx = min(max(nx, 0), WW - 1);

        float vec[D];
        float nrm2 = 0.0f;
        int k = 0;
        #pragma unroll
        for (int dy = -1; dy <= 1; ++dy) {
            const int py = min(max(cy + dy, 0), HH - 1);
            #pragma unroll
            for (int dx = -1; dx <= 1; ++dx) {
                const int px = min(max(cx + dx, 0), WW - 1);
                const float* p = latents + (((size_t)b * HH + py) * WW + px) * CC;
                #pragma unroll
                for (int c = 0; c < CC; ++c) {
                    const float f = p[c];
                    vec[k++] = f;
                    nrm2 += f * f;
                }
            }
        }
        const float inv = 1.0f / fmaxf(sqrtf(nrm2), 1e-12f);
        #pragma unroll
        for (int kk = 0; kk < D; ++kk) v[task][kk] = vec[kk] * inv;
    }

    // Validity mask + count (cheap; computed redundantly by every thread).
    int validmask = 0;
    int counts = 0;
    #pragma unroll
    for (int m = 0; m < M; ++m) {
        const int ny = ay + ODY[m];
        const int nx = ax + ODX[m];
        const int ok = (ny >= 0) && (ny < HH) && (nx >= 0) && (nx < WW);
        validmask |= ok << m;
        counts += ok;
    }

    __syncthreads();

    // Stage 2: 9*9*13 = 1053 (b,j,m) dot-square tasks; skip b==j and invalid m.
    float acc = 0.0f;
    for (int task = t; task < BB * BB * M; task += 128) {
        const int b = task / (BB * M);
        const int rem = task - b * (BB * M);
        const int j = rem / M;
        const int m = rem - j * M;
        if (b == j) continue;
        if (!((validmask >> m) & 1)) continue;
        const float* a = v[b * M + M0];
        const float* u = v[j * M + m];
        float dot = 0.0f;
        #pragma unroll
        for (int kk = 0; kk < D; ++kk) dot += a[kk] * u[kk];
        acc += dot * dot;
    }

    // Block reduction (2 waves of 64).
    #pragma unroll
    for (int off = 32; off > 0; off >>= 1) acc += __shfl_down(acc, off, 64);
    if ((t & 63) == 0) wsum[t >> 6] = acc;
    __syncthreads();
    if (t == 0) {
        const float s = wsum[0] + wsum[1];
        // (1/T^2)=4 ; K=8 ; mean over B*N = 900
        const float scale = 4.0f / (8.0f * (float)counts * (float)(BB * NS));
        partial[n] = s * scale;
    }
}

__global__ __launch_bounds__(128)
void BatchInfoNCELoss_reduce_kernel(const float* __restrict__ partial,
                                    float* __restrict__ out) {
    const int t = threadIdx.x;  // 0..127
    float a = (t < NS) ? partial[t] : 0.0f;
    #pragma unroll
    for (int off = 32; off > 0; off >>= 1) a += __shfl_down(a, off, 64);
    __shared__ float w[2];
    if ((t & 63) == 0) w[t >> 6] = a;
    __syncthreads();
    if (t == 0) out[0] = w[0] + w[1];
}

extern "C" void kernel_launch(void* const* d_in, const int* in_sizes, int n_in,
                              void* d_out, int out_size, void* d_ws, size_t ws_size,
                              hipStream_t stream) {
    const float* latents = (const float*)d_in[0];
    const int*   aidx    = (const int*)d_in[1];
    float* out     = (float*)d_out;
    float* partial = (float*)d_ws;  // NS floats of scratch

    BatchInfoNCELoss_anchor_kernel<<<NS, 128, 0, stream>>>(latents, aidx, partial);
    BatchInfoNCELoss_reduce_kernel<<<1, 128, 0, stream>>>(partial, out);
}